// Round 5
// baseline (180.927 us; speedup 1.0000x reference)
//
#include <hip/hip_runtime.h>

// FWHT of 2^24 float32, output scaled by 1/2^24.
// R5 = MEASUREMENT ROUND: exact R0-baseline kernels (best: 133.6 us), but
// pass1 is launched 3x (idempotent: out-of-place in->out, same result every
// time) + pass2 1x. dur_us delta vs 133.6 directly measures pass1's
// duration: pass1 = (dur - 133.6)/2 - ~2us gap. If pass1 > 40.84 us it also
// surfaces in the rocprof top-5 with its own counters (FETCH/WRITE split).
// History: pass2 v1 64B: 2.85 TB/s; v2 128B: ~3.3 (R0 best, this file);
//   v3 256B: NULL; v4 XCD-gang: NULL; R3 coop fusion: FAILED (launch
//   rejected, zero output); R4 float2 everywhere: -10us REGRESSION
//   (suspect VGPR spill in pass2 + predicated half-idle LDS writes).
// Accounting model to verify: fill(42) + pass1(~40?) + pass2(~40?) + gaps.

#define N_LOG2 24
#define CHUNK_LOG2 14           // pass-1 chunk = 16384 elements = 64 KB LDS
#define CHUNK (1 << CHUNK_LOG2)

// Pass-1 LDS swizzle: flips addr bits 2-4 with (row ^ row>>2)&7, row = e>>5.
// All pass-1 LDS phases land at <=2 lanes/bank (free per m136); keeps 16 B
// alignment for float4 stores.
static __device__ __forceinline__ int swz(int e) {
  return e ^ ((((e >> 5) ^ (e >> 7)) & 7) << 2);
}

static __device__ __forceinline__ void fwht32(float* v) {
#pragma unroll
  for (int h = 1; h < 32; h <<= 1) {
#pragma unroll
    for (int g = 0; g < 32; g += 2 * h) {
#pragma unroll
      for (int k = 0; k < h; ++k) {
        float a = v[g + k], b = v[g + k + h];
        v[g + k] = a + b;
        v[g + k + h] = a - b;
      }
    }
  }
}

static __device__ __forceinline__ void fwht16(float* v) {
#pragma unroll
  for (int h = 1; h < 16; h <<= 1) {
#pragma unroll
    for (int g = 0; g < 16; g += 2 * h) {
#pragma unroll
      for (int k = 0; k < h; ++k) {
        float a = v[g + k], b = v[g + k + h];
        v[g + k] = a + b;
        v[g + k + h] = a - b;
      }
    }
  }
}

// Pass 1: per-block contiguous chunk of 16384 floats; stages over bits 0-13.
// (exact R0 version)
__global__ __launch_bounds__(512) void fwht_pass1(const float* __restrict__ in,
                                                  float* __restrict__ out) {
  __shared__ float lds[CHUNK];
  const int t = threadIdx.x;                 // [0, 512)
  const int base = (int)blockIdx.x << CHUNK_LOG2;
  float v[32];

  // Group 0: thread owns contiguous e = 32t .. 32t+31 (bits 0-4).
  const float4* g4 = reinterpret_cast<const float4*>(in + base) + t * 8;
#pragma unroll
  for (int q = 0; q < 8; ++q) {
    float4 f = g4[q];
    v[4 * q + 0] = f.x; v[4 * q + 1] = f.y;
    v[4 * q + 2] = f.z; v[4 * q + 3] = f.w;
  }
  fwht32(v);  // bits 0-4
#pragma unroll
  for (int q = 0; q < 8; ++q) {
    int e = t * 32 + q * 4;
    *reinterpret_cast<float4*>(&lds[swz(e)]) =
        make_float4(v[4 * q], v[4 * q + 1], v[4 * q + 2], v[4 * q + 3]);
  }
  __syncthreads();

  // Group 1: thread owns e = lo + (j<<5) + (hi<<10), j = 0..31 (bits 5-9).
  const int lo = t & 31, hi = t >> 5;        // hi in [0,16)
#pragma unroll
  for (int j = 0; j < 32; ++j) v[j] = lds[swz(lo + (j << 5) + (hi << 10))];
  fwht32(v);  // bits 5-9
#pragma unroll
  for (int j = 0; j < 32; ++j) lds[swz(lo + (j << 5) + (hi << 10))] = v[j];
  __syncthreads();

  // Group 2: thread owns e = f + (jr<<10) for f = t, t+512 (bits 10-13).
#pragma unroll
  for (int b = 0; b < 2; ++b) {
    int f = t + (b << 9);
#pragma unroll
    for (int jr = 0; jr < 16; ++jr) v[b * 16 + jr] = lds[swz(f + (jr << 10))];
  }
  fwht16(v);
  fwht16(v + 16);
#pragma unroll
  for (int b = 0; b < 2; ++b) {
    int f = t + (b << 9);
#pragma unroll
    for (int jr = 0; jr < 16; ++jr) out[base + f + (jr << 10)] = v[b * 16 + jr];
  }
}

// Pass 2 (exact R0 v2): view i = r*16384 + c, r in [0,1024), c in [0,16384).
// Block owns a 1024-row x 32-col tile (grid 512). Thread t: c = t&31,
// rgrp = t>>5 in [0,16). A-phase rows rgrp*32+j / (rgrp+16)*32+j -> bits
// 14-18; exchange via 64 KB LDS in two 512-row halves (3 barriers); B-phase
// rows rgrp+32j / rgrp+16+32j -> bits 19-23; applies 1/N. All LDS phases
// 2 lanes/bank (free). In-place safe: loads precede first barrier, stores
// follow last read; blocks own disjoint columns.
__global__ __launch_bounds__(512, 4) void fwht_pass2(float* __restrict__ io) {
  __shared__ float lds[CHUNK];               // 16384 floats = 64 KB
  const int t = threadIdx.x;                 // [0, 512)
  const int c = t & 31, rgrp = t >> 5;       // rgrp in [0,16)
  const int cbase = (int)blockIdx.x * 32;
  float v0[32], v1[32], u0[32], u1[32];

  // A: v0[j] = elem(r = rgrp*32 + j), v1[j] = elem(r = (rgrp+16)*32 + j).
#pragma unroll
  for (int j = 0; j < 32; ++j)
    v0[j] = io[(rgrp * 32 + j) * CHUNK + cbase + c];
#pragma unroll
  for (int j = 0; j < 32; ++j)
    v1[j] = io[((rgrp + 16) * 32 + j) * CHUNK + cbase + c];
  fwht32(v0);  // global bits 14-18 (rows 0-511 group)
  fwht32(v1);  // global bits 14-18 (rows 512-1023 group)

  // Half 0: rows r in [0,512) == all of v0. LDS idx = r*32 + c.
#pragma unroll
  for (int j = 0; j < 32; ++j)
    lds[rgrp * 1024 + j * 32 + c] = v0[j];   // r = rgrp*32+j
  __syncthreads();
  // B wants u0[j] = elem(r = rgrp + 32j), u1[j] = elem(r = rgrp+16 + 32j).
  // Half 0 supplies j in [0,16): idx = (rlo + 32j)*32 + c.
#pragma unroll
  for (int j = 0; j < 16; ++j)
    u0[j] = lds[rgrp * 32 + j * 1024 + c];
#pragma unroll
  for (int j = 0; j < 16; ++j)
    u1[j] = lds[(rgrp + 16) * 32 + j * 1024 + c];
  __syncthreads();

  // Half 1: rows r in [512,1024) == all of v1. LDS idx = (r-512)*32 + c.
#pragma unroll
  for (int j = 0; j < 32; ++j)
    lds[rgrp * 1024 + j * 32 + c] = v1[j];   // r-512 = rgrp*32+j
  __syncthreads();
  // Half 1 supplies j in [16,32): idx = (rlo + 32(j-16))*32 + c.
#pragma unroll
  for (int j = 16; j < 32; ++j)
    u0[j] = lds[rgrp * 32 + (j - 16) * 1024 + c];
#pragma unroll
  for (int j = 16; j < 32; ++j)
    u1[j] = lds[(rgrp + 16 + 32 * (j - 16)) * 32 + c];

  fwht32(u0);  // global bits 19-23
  fwht32(u1);
  const float s = 1.0f / 16777216.0f;
#pragma unroll
  for (int j = 0; j < 32; ++j)
    io[(rgrp + 32 * j) * CHUNK + cbase + c] = u0[j] * s;
#pragma unroll
  for (int j = 0; j < 32; ++j)
    io[(rgrp + 16 + 32 * j) * CHUNK + cbase + c] = u1[j] * s;
}

extern "C" void kernel_launch(void* const* d_in, const int* in_sizes, int n_in,
                              void* d_out, int out_size, void* d_ws, size_t ws_size,
                              hipStream_t stream) {
  const float* in = (const float*)d_in[0];
  float* out = (float*)d_out;
  // MEASUREMENT: pass1 launched 3x (idempotent, identical output) so the
  // dur_us delta vs the 133.6 us single-launch baseline = 2 x pass1.
  fwht_pass1<<<1024, 512, 0, stream>>>(in, out);
  fwht_pass1<<<1024, 512, 0, stream>>>(in, out);
  fwht_pass1<<<1024, 512, 0, stream>>>(in, out);
  fwht_pass2<<<512, 512, 0, stream>>>(out);
}